// Round 19
// baseline (51.354 us; speedup 1.0000x reference)
//
#include <hip/hip_runtime.h>
#include <hip/hip_bf16.h>

// Problem constants
#define BB 8
#define L1 64
#define LL 1024
#define DD 512   // DIM_IN == DIM_H == DIM_M == 512

typedef float f32x4 __attribute__((ext_vector_type(4)));
typedef _Float16 f16;
typedef _Float16 f16x2 __attribute__((ext_vector_type(2)));
typedef _Float16 f16x4 __attribute__((ext_vector_type(4)));
typedef _Float16 f16x8 __attribute__((ext_vector_type(8)));

union F16x8u { f16x8 v; f16x2 h[4]; };
union U4H8 { uint4 u; f16x8 v; };

// ---------------------------------------------------------------------------
// K1: combined kx + qh GEMM.  (r15 — best measured, unchanged)
// grid 1032, 256 thr:
//   bid 0..7    : qh[q,m] = query @ Wh^T + bh (m-tile of 64).
//   bid 8..1031 : kx 64x64 tile; kb=bid-8, rt=kb&127, mt=kb>>7.
// 64x64 tile -> ~80 VGPR, 32KB dbuf LDS -> ~4 blocks/CU.
// BK=64, ONE barrier/step, T14 reg prefetch, XOR-swizzled LDS.
// ---------------------------------------------------------------------------
__global__ __launch_bounds__(256) void kxqh_kernel(
    const float* __restrict__ keys,   // [8192,512] f32
    const float* __restrict__ query,  // [64,512]   f32
    const float* __restrict__ Wx,     // [512,512]  f32
    const float* __restrict__ Wh,     // [512,512]  f32
    const float* __restrict__ bh,     // [512]      f32
    f16* __restrict__ kx,             // [8192,512] f16
    f16* __restrict__ qh) {           // [64,512]   f16
  __shared__ char lds[32768] __attribute__((aligned(128)));
  const int t = threadIdx.x;
  const int lane = t & 63;
  const int w = t >> 6;
  const int fq = lane >> 4, fr = lane & 15;
  const int bid = blockIdx.x;

  if (bid < 8) {
    // ---------------- qh path ----------------
    const int m0 = bid * 64;
    const int wid = w;
    f32x4 acc[4] = {};
    float4 rq[4], rw[4];
#define LOADQ(KC)                                                              \
    do {                                                                       \
      _Pragma("unroll") for (int i = 0; i < 4; ++i) {                          \
        int slot = t + i * 256;                                                \
        int row = slot >> 4, c4 = (slot & 15) * 4;                             \
        rq[i] = *reinterpret_cast<const float4*>(query + (size_t)row * DD + (KC)*64 + c4); \
        rw[i] = *reinterpret_cast<const float4*>(Wh + (size_t)(m0 + row) * DD + (KC)*64 + c4); \
      }                                                                        \
    } while (0)
    LOADQ(0);
    for (int kc = 0; kc < 8; ++kc) {
      #pragma unroll
      for (int i = 0; i < 4; ++i) {
        int slot = t + i * 256;
        int row = slot >> 4, c4 = (slot & 15) * 4;
        f16x4 hq, hw;
        hq[0] = (f16)rq[i].x; hq[1] = (f16)rq[i].y; hq[2] = (f16)rq[i].z; hq[3] = (f16)rq[i].w;
        hw[0] = (f16)rw[i].x; hw[1] = (f16)rw[i].y; hw[2] = (f16)rw[i].z; hw[3] = (f16)rw[i].w;
        *reinterpret_cast<f16x4*>(lds + row * 144 + c4 * 2) = hq;
        *reinterpret_cast<f16x4*>(lds + 9216 + row * 144 + c4 * 2) = hw;
      }
      if (kc < 7) LOADQ(kc + 1);
      __syncthreads();
      #pragma unroll
      for (int kh = 0; kh < 2; ++kh) {
        f16x8 bf = *reinterpret_cast<const f16x8*>(
            lds + 9216 + (wid * 16 + fr) * 144 + kh * 64 + fq * 16);
        #pragma unroll
        for (int qf = 0; qf < 4; ++qf) {
          f16x8 af = *reinterpret_cast<const f16x8*>(
              lds + (qf * 16 + fr) * 144 + kh * 64 + fq * 16);
          acc[qf] = __builtin_amdgcn_mfma_f32_16x16x32_f16(af, bf, acc[qf], 0, 0, 0);
        }
      }
      __syncthreads();
    }
#undef LOADQ
    #pragma unroll
    for (int qf = 0; qf < 4; ++qf) {
      int m = m0 + wid * 16 + fr;
      float bias = bh[m];
      #pragma unroll
      for (int r = 0; r < 4; ++r)
        qh[(size_t)(qf * 16 + fq * 4 + r) * DD + m] = (f16)(acc[qf][r] + bias);
    }
    return;
  }

  // ---------------- kx path: 64x64 tile ----------------
  const int kb = bid - 8;
  const int rt = kb & 127;
  const int mt = kb >> 7;          // 0..7
  const int rowA0 = rt * 64;
  const int m0 = mt * 64;
  const int wr = w >> 1, wc = w & 1;

  f32x4 acc[2][2] = {};
  float4 ra[4], rb[4];

#define LOADK(K0)                                                              \
  do {                                                                         \
    _Pragma("unroll") for (int i = 0; i < 4; ++i) {                            \
      int flat = t * 4 + i * 1024;                                             \
      int row = flat >> 6, col = flat & 63;                                    \
      ra[i] = *reinterpret_cast<const float4*>(keys + (size_t)(rowA0 + row) * DD + (K0) + col); \
      rb[i] = *reinterpret_cast<const float4*>(Wx + (size_t)(m0 + row) * DD + (K0) + col); \
    }                                                                          \
  } while (0)

  LOADK(0);
  for (int s = 0; s < 8; ++s) {
    const int base = (s & 1) * 16384;   // A @ base, B @ base+8192
    #pragma unroll
    for (int i = 0; i < 4; ++i) {
      int flat = t * 4 + i * 1024;
      int row = flat >> 6, col = flat & 63;
      f16x4 ha, hb;
      ha[0] = (f16)ra[i].x; ha[1] = (f16)ra[i].y; ha[2] = (f16)ra[i].z; ha[3] = (f16)ra[i].w;
      hb[0] = (f16)rb[i].x; hb[1] = (f16)rb[i].y; hb[2] = (f16)rb[i].z; hb[3] = (f16)rb[i].w;
      int byte = row * 128 + ((col * 2) ^ ((row & 7) << 4));
      *reinterpret_cast<f16x4*>(lds + base + byte) = ha;
      *reinterpret_cast<f16x4*>(lds + base + 8192 + byte) = hb;
    }
    if (s < 7) LOADK((s + 1) * 64);   // in flight across compute
    __syncthreads();                  // single barrier per step (dbuf-safe)
    #pragma unroll
    for (int kh = 0; kh < 2; ++kh) {
      f16x8 af[2], bf[2];
      #pragma unroll
      for (int mi = 0; mi < 2; ++mi) {
        int row = wr * 32 + mi * 16 + fr;
        af[mi] = *reinterpret_cast<const f16x8*>(
            lds + base + row * 128 + ((kh * 64 + fq * 16) ^ ((row & 7) << 4)));
      }
      #pragma unroll
      for (int ni = 0; ni < 2; ++ni) {
        int row = wc * 32 + ni * 16 + fr;
        bf[ni] = *reinterpret_cast<const f16x8*>(
            lds + base + 8192 + row * 128 + ((kh * 64 + fq * 16) ^ ((row & 7) << 4)));
      }
      #pragma unroll
      for (int mi = 0; mi < 2; ++mi)
        #pragma unroll
        for (int ni = 0; ni < 2; ++ni)
          acc[mi][ni] = __builtin_amdgcn_mfma_f32_16x16x32_f16(
              af[mi], bf[ni], acc[mi][ni], 0, 0, 0);
    }
  }
#undef LOADK
  #pragma unroll
  for (int mi = 0; mi < 2; ++mi) {
    #pragma unroll
    for (int ni = 0; ni < 2; ++ni) {
      int row = rowA0 + wr * 32 + mi * 16 + fq * 4;
      int col = m0 + wc * 32 + ni * 16 + fr;
      #pragma unroll
      for (int r = 0; r < 4; ++r)
        kx[(size_t)(row + r) * DD + col] = (f16)acc[mi][ni][r];
    }
  }
}

// ---------------------------------------------------------------------------
// K2: score10 — 256 threads, 4l x 2q register tile (LDS reads/output cut 25%:
// (1/4 + 1/2) vs (1/2 + 1/2)).  Block = (b, l-tile 64, q-half 32); grid 256 =
// 8b x 16lt x 2qh.  Swizzles: kxs swz=((row>>2)&15)<<4 (16 distinct slot cols
// for the 16 lg rows per wave); qhs swz=((row>>1)&15)<<4 (4 distinct + bcast).
// T14 prefetch of next m-chunk.  sc f16 + pmax epilogue (2 halves per block).
// ---------------------------------------------------------------------------
__global__ __launch_bounds__(256) void score10_kernel(
    const f16* __restrict__ kx,   // [8,1024,512] f16
    const f16* __restrict__ qh,   // [64,512] f16
    const float* __restrict__ w,  // [512] f32
    f16* __restrict__ sc,         // [8,64,1024] f16
    float* __restrict__ pmax) {   // [8,64,32] f32
  const int bid = blockIdx.x;
  const int b = bid & 7;
  const int lt = (bid >> 3) & 15;
  const int l0 = lt * 64;
  const int q0 = (bid >> 7) * 32;
  const int t = threadIdx.x;
  __shared__ __align__(16) char kxs[64 * 256];   // row*256 + (col2 ^ ((row>>2&15)<<4))
  __shared__ __align__(16) char qhs[32 * 256];   // row*256 + (col2 ^ ((row>>1&15)<<4))
  __shared__ __align__(16) f16 wsf[DD];
  __shared__ float smax[32][17];
  if (t < 128) {
    float4 wv = *reinterpret_cast<const float4*>(w + t * 4);
    f16x4 hv; hv[0] = (f16)wv.x; hv[1] = (f16)wv.y; hv[2] = (f16)wv.z; hv[3] = (f16)wv.w;
    *reinterpret_cast<f16x4*>(&wsf[t * 4]) = hv;
  }
  const int lg = t & 15;    // l-group: l = l0 + lg*4 + i
  const int qg = t >> 4;    // q-group: q = q0 + qg*2 + j
  float acc[4][2] = {};
  uint4 rkx[4], rqh[2];

#define LOADM(M0)                                                              \
  do {                                                                         \
    _Pragma("unroll") for (int p = 0; p < 4; ++p) {                            \
      int slot = t + p * 256;                                                  \
      int row = slot >> 4, col = (slot & 15) * 8;                              \
      rkx[p] = *reinterpret_cast<const uint4*>(kx + (size_t)(b * LL + l0 + row) * DD + (M0) + col); \
    }                                                                          \
    _Pragma("unroll") for (int p = 0; p < 2; ++p) {                            \
      int slot = t + p * 256;                                                  \
      int row = slot >> 4, col = (slot & 15) * 8;                              \
      rqh[p] = *reinterpret_cast<const uint4*>(qh + (size_t)(q0 + row) * DD + (M0) + col); \
    }                                                                          \
  } while (0)

  LOADM(0);
  for (int m0 = 0; m0 < DD; m0 += 128) {
    #pragma unroll
    for (int p = 0; p < 4; ++p) {
      int slot = t + p * 256;
      int row = slot >> 4, cb = (slot & 15) * 16;
      *reinterpret_cast<uint4*>(kxs + row * 256 + (cb ^ (((row >> 2) & 15) << 4))) = rkx[p];
    }
    #pragma unroll
    for (int p = 0; p < 2; ++p) {
      int slot = t + p * 256;
      int row = slot >> 4, cb = (slot & 15) * 16;
      *reinterpret_cast<uint4*>(qhs + row * 256 + (cb ^ (((row >> 1) & 15) << 4))) = rqh[p];
    }
    if (m0 < DD - 128) LOADM(m0 + 128);
    __syncthreads();
    #pragma unroll 2
    for (int mm = 0; mm < 128; mm += 8) {
      const int mb = mm * 2;
      F16x8u kv[4], wv, qv[2];
      #pragma unroll
      for (int i = 0; i < 4; ++i) {
        int row = lg * 4 + i;
        kv[i].v = *reinterpret_cast<const f16x8*>(
            kxs + row * 256 + (mb ^ (((row >> 2) & 15) << 4)));
      }
      wv.v = *reinterpret_cast<const f16x8*>(&wsf[m0 + mm]);
      #pragma unroll
      for (int j = 0; j < 2; ++j) {
        int row = qg * 2 + j;
        qv[j].v = *reinterpret_cast<const f16x8*>(
            qhs + row * 256 + (mb ^ (((row >> 1) & 15) << 4)));
      }
      #pragma unroll
      for (int i = 0; i < 4; ++i) {
        #pragma unroll
        for (int j = 0; j < 2; ++j) {
          f16x8 zz = {};
          F16x8u g;
          g.v = __builtin_elementwise_max(kv[i].v + qv[j].v, zz);
          #pragma unroll
          for (int c = 0; c < 4; ++c)
            acc[i][j] = __builtin_amdgcn_fdot2(g.h[c], wv.h[c], acc[i][j], false);
        }
      }
    }
    __syncthreads();
  }
#undef LOADM
  // ---- epilogue: sc (f16) + pmax (two 32-l halves per block) ----
  #pragma unroll
  for (int i = 0; i < 4; ++i)
    #pragma unroll
    for (int j = 0; j < 2; ++j)
      sc[((size_t)b * L1 + q0 + qg * 2 + j) * LL + l0 + lg * 4 + i] = (f16)acc[i][j];
  #pragma unroll
  for (int j = 0; j < 2; ++j) {
    float m = fmaxf(fmaxf(acc[0][j], acc[1][j]), fmaxf(acc[2][j], acc[3][j]));
    smax[qg * 2 + j][lg] = m;   // thread's 4 l's lie in one 32-half (lg<8 or >=8)
  }
  __syncthreads();
  if (t < 64) {
    int qr = t >> 1, half = t & 1;
    float m = smax[qr][half * 8];
    #pragma unroll
    for (int i = 1; i < 8; ++i) m = fmaxf(m, smax[qr][half * 8 + i]);
    pmax[((size_t)b * L1 + q0 + qr) * 32 + lt * 2 + half] = m;
  }
}

// ---------------------------------------------------------------------------
// K3: fused softmax + PV GEMM — 512 thr, ks-split; sc in f16.  (r13's fso3)
// ---------------------------------------------------------------------------
__global__ __launch_bounds__(512) void fso3_kernel(
    const f16* __restrict__ sc,     // [8,64,1024] f16
    const float* __restrict__ pmax, // [8,64,32] f32
    const float* __restrict__ v,    // [8,1024,512] f32
    float* __restrict__ out) {      // [8,64,512] f32
  __shared__ __align__(16) char es[64 * 256];
  __shared__ __align__(16) char vt[16 * 256];
  __shared__ float rowm[64];
  __shared__ float rowinv[64];
  __shared__ float spart[64][17];
  __shared__ f32x4 accbuf[4][64];
  const int t = threadIdx.x;
  const int lane = t & 63;
  const int w = t >> 6;
  const int fq = lane >> 4, fr = lane & 15;
  const int bid = blockIdx.x;
  const int b = bid & 7;
  const int d0 = (bid >> 3) * 16;
  const f16* scb = sc + (size_t)b * L1 * LL;
  const float* vb = v + (size_t)b * LL * DD;

  const int r0 = t >> 4;
  const int r1 = (t + 512) >> 4;
  const int ec8 = t & 15;
  const int vl = t >> 2;
  const int dq = (t & 3) * 4;
  uint4 rsc[2];
  float4 rv;

#define LOADC(LC)                                                              \
  do {                                                                         \
    rsc[0] = *reinterpret_cast<const uint4*>(scb + (size_t)r0 * LL + (LC) * 128 + ec8 * 8); \
    rsc[1] = *reinterpret_cast<const uint4*>(scb + (size_t)r1 * LL + (LC) * 128 + ec8 * 8); \
    rv = *reinterpret_cast<const float4*>(                                     \
        vb + (size_t)((LC) * 128 + vl) * DD + d0 + dq);                        \
  } while (0)

  LOADC(0);
  if (t < 64) {
    const float* pm = pmax + ((size_t)b * L1 + t) * 32;
    float4 m4 = *reinterpret_cast<const float4*>(pm);
    #pragma unroll
    for (int i = 1; i < 8; ++i) {
      float4 x = *reinterpret_cast<const float4*>(pm + i * 4);
      m4.x = fmaxf(m4.x, x.x); m4.y = fmaxf(m4.y, x.y);
      m4.z = fmaxf(m4.z, x.z); m4.w = fmaxf(m4.w, x.w);
    }
    rowm[t] = fmaxf(fmaxf(m4.x, m4.y), fmaxf(m4.z, m4.w));
  }
  __syncthreads();
  float rmv[2] = {rowm[r0], rowm[r1]};
  float spp[2] = {0.f, 0.f};
  f32x4 acc = {};
  const int qs = (w & 3) * 16;
  const int ksh = (w >> 2) * 2;

  for (int c = 0; c < 8; ++c) {
    #pragma unroll
    for (int p = 0; p < 2; ++p) {
      int q = p ? r1 : r0;
      U4H8 x; x.u = rsc[p];
      f16x8 h;
      #pragma unroll
      for (int j = 0; j < 8; ++j) {
        float e = __expf((float)x.v[j] - rmv[p]);
        spp[p] += e;
        h[j] = (f16)e;
      }
      int byte = q * 256 + ((ec8 * 16) ^ ((q & 7) << 4));
      *reinterpret_cast<f16x8*>(es + byte) = h;
    }
    {
      float vs[4] = {rv.x, rv.y, rv.z, rv.w};
      #pragma unroll
      for (int j = 0; j < 4; ++j) {
        int d = dq + j;
        int byte = d * 256 + ((2 * vl) ^ ((d & 7) << 4));
        *reinterpret_cast<f16*>(vt + byte) = (f16)vs[j];
      }
    }
    if (c < 7) LOADC(c + 1);
    __syncthreads();
    #pragma unroll
    for (int ki = 0; ki < 2; ++ki) {
      int ks = ksh + ki;
      int qa = qs + fr;
      int colb = ks * 64 + fq * 16;
      f16x8 a = *reinterpret_cast<const f16x8*>(es + qa * 256 + (colb ^ ((qa & 7) << 4)));
      f16x8 bb = *reinterpret_cast<const f16x8*>(vt + fr * 256 + (colb ^ ((fr & 7) << 4)));
      acc = __builtin_amdgcn_mfma_f32_16x16x32_f16(a, bb, acc, 0, 0, 0);
    }
    __syncthreads();
  }
#undef LOADC
  spart[r0][ec8] = spp[0];
  spart[r1][ec8] = spp[1];
  if (w >= 4) accbuf[w & 3][lane] = acc;
  __syncthreads();
  if (t < 64) {
    float S = 0.f;
    #pragma unroll
    for (int i = 0; i < 16; ++i) S += spart[t][i];
    rowinv[t] = 1.f / S;
  }
  __syncthreads();
  if (w < 4) {
    f32x4 ah = accbuf[w][lane];
    acc += ah;
    #pragma unroll
    for (int r = 0; r < 4; ++r) {
      int q = qs + fq * 4 + r;
      out[((size_t)b * L1 + q) * DD + d0 + fr] = acc[r] * rowinv[q];
    }
  }
}

// ---------------------------------------------------------------------------
extern "C" void kernel_launch(void* const* d_in, const int* in_sizes, int n_in,
                              void* d_out, int out_size, void* d_ws, size_t ws_size,
                              hipStream_t stream) {
  const float* query  = (const float*)d_in[0];  // [64,512]
  const float* keys   = (const float*)d_in[1];  // [8,1024,512]
  const float* values = (const float*)d_in[2];  // [8,1024,512]
  const float* Wx     = (const float*)d_in[3];  // [512,512]
  const float* Wh     = (const float*)d_in[4];  // [512,512]
  const float* bh     = (const float*)d_in[5];  // [512]
  const float* w      = (const float*)d_in[6];  // [512]
  float* out = (float*)d_out;                   // [8,64,512]

  char* ws = (char*)d_ws;
  f16*   kx   = (f16*)ws;                        // 8 MB
  f16*   qh   = (f16*)(ws + 8388608);            // 64 KB
  f16*   sc   = (f16*)(ws + 8454144);            // 1 MB (f16 scores)
  float* pmax = (float*)(ws + 9502720);          // 64 KB

  kxqh_kernel<<<1032, 256, 0, stream>>>(keys, query, Wx, Wh, bh, kx, qh);
  score10_kernel<<<256, 256, 0, stream>>>(kx, qh, w, sc, pmax);
  fso3_kernel<<<256, 512, 0, stream>>>(sc, pmax, values, out);
}

// Round 20
// 47.917 us; speedup vs baseline: 1.0717x; 1.0717x over previous
//
#include <hip/hip_runtime.h>
#include <hip/hip_bf16.h>

// Problem constants
#define BB 8
#define L1 64
#define LL 1024
#define DD 512   // DIM_IN == DIM_H == DIM_M == 512

typedef float f32x4 __attribute__((ext_vector_type(4)));
typedef _Float16 f16;
typedef _Float16 f16x2 __attribute__((ext_vector_type(2)));
typedef _Float16 f16x4 __attribute__((ext_vector_type(4)));
typedef _Float16 f16x8 __attribute__((ext_vector_type(8)));

union F16x8u { f16x8 v; f16x2 h[4]; };
union U4H8 { uint4 u; f16x8 v; };

// ---------------------------------------------------------------------------
// K1: combined kx + qh GEMM.  (r15 — best measured; bid==0 also emits w16)
// grid 1032, 256 thr:
//   bid 0..7    : qh[q,m] = query @ Wh^T + bh (m-tile of 64).
//   bid 8..1031 : kx 64x64 tile; kb=bid-8, rt=kb&127, mt=kb>>7.
// ---------------------------------------------------------------------------
__global__ __launch_bounds__(256) void kxqh_kernel(
    const float* __restrict__ keys,   // [8192,512] f32
    const float* __restrict__ query,  // [64,512]   f32
    const float* __restrict__ Wx,     // [512,512]  f32
    const float* __restrict__ Wh,     // [512,512]  f32
    const float* __restrict__ bh,     // [512]      f32
    const float* __restrict__ w,      // [512]      f32
    f16* __restrict__ kx,             // [8192,512] f16
    f16* __restrict__ qh,             // [64,512]   f16
    f16* __restrict__ w16) {          // [512]      f16
  __shared__ char lds[32768] __attribute__((aligned(128)));
  const int t = threadIdx.x;
  const int lane = t & 63;
  const int wv_ = t >> 6;
  const int fq = lane >> 4, fr = lane & 15;
  const int bid = blockIdx.x;

  if (bid < 8) {
    // ---------------- qh path ----------------
    if (bid == 0 && t < 128) {   // w -> f16 (same RNE cast as before)
      float4 x = *reinterpret_cast<const float4*>(w + t * 4);
      f16x4 h; h[0] = (f16)x.x; h[1] = (f16)x.y; h[2] = (f16)x.z; h[3] = (f16)x.w;
      *reinterpret_cast<f16x4*>(w16 + t * 4) = h;
    }
    const int m0 = bid * 64;
    const int wid = wv_;
    f32x4 acc[4] = {};
    float4 rq[4], rw[4];
#define LOADQ(KC)                                                              \
    do {                                                                       \
      _Pragma("unroll") for (int i = 0; i < 4; ++i) {                          \
        int slot = t + i * 256;                                                \
        int row = slot >> 4, c4 = (slot & 15) * 4;                             \
        rq[i] = *reinterpret_cast<const float4*>(query + (size_t)row * DD + (KC)*64 + c4); \
        rw[i] = *reinterpret_cast<const float4*>(Wh + (size_t)(m0 + row) * DD + (KC)*64 + c4); \
      }                                                                        \
    } while (0)
    LOADQ(0);
    for (int kc = 0; kc < 8; ++kc) {
      #pragma unroll
      for (int i = 0; i < 4; ++i) {
        int slot = t + i * 256;
        int row = slot >> 4, c4 = (slot & 15) * 4;
        f16x4 hq, hw;
        hq[0] = (f16)rq[i].x; hq[1] = (f16)rq[i].y; hq[2] = (f16)rq[i].z; hq[3] = (f16)rq[i].w;
        hw[0] = (f16)rw[i].x; hw[1] = (f16)rw[i].y; hw[2] = (f16)rw[i].z; hw[3] = (f16)rw[i].w;
        *reinterpret_cast<f16x4*>(lds + row * 144 + c4 * 2) = hq;
        *reinterpret_cast<f16x4*>(lds + 9216 + row * 144 + c4 * 2) = hw;
      }
      if (kc < 7) LOADQ(kc + 1);
      __syncthreads();
      #pragma unroll
      for (int kh = 0; kh < 2; ++kh) {
        f16x8 bf = *reinterpret_cast<const f16x8*>(
            lds + 9216 + (wid * 16 + fr) * 144 + kh * 64 + fq * 16);
        #pragma unroll
        for (int qf = 0; qf < 4; ++qf) {
          f16x8 af = *reinterpret_cast<const f16x8*>(
              lds + (qf * 16 + fr) * 144 + kh * 64 + fq * 16);
          acc[qf] = __builtin_amdgcn_mfma_f32_16x16x32_f16(af, bf, acc[qf], 0, 0, 0);
        }
      }
      __syncthreads();
    }
#undef LOADQ
    #pragma unroll
    for (int qf = 0; qf < 4; ++qf) {
      int m = m0 + wid * 16 + fr;
      float bias = bh[m];
      #pragma unroll
      for (int r = 0; r < 4; ++r)
        qh[(size_t)(qf * 16 + fq * 4 + r) * DD + m] = (f16)(acc[qf][r] + bias);
    }
    return;
  }

  // ---------------- kx path: 64x64 tile ----------------
  const int kb = bid - 8;
  const int rt = kb & 127;
  const int mt = kb >> 7;          // 0..7
  const int rowA0 = rt * 64;
  const int m0 = mt * 64;
  const int wr = wv_ >> 1, wc = wv_ & 1;

  f32x4 acc[2][2] = {};
  float4 ra[4], rb[4];

#define LOADK(K0)                                                              \
  do {                                                                         \
    _Pragma("unroll") for (int i = 0; i < 4; ++i) {                            \
      int flat = t * 4 + i * 1024;                                             \
      int row = flat >> 6, col = flat & 63;                                    \
      ra[i] = *reinterpret_cast<const float4*>(keys + (size_t)(rowA0 + row) * DD + (K0) + col); \
      rb[i] = *reinterpret_cast<const float4*>(Wx + (size_t)(m0 + row) * DD + (K0) + col); \
    }                                                                          \
  } while (0)

  LOADK(0);
  for (int s = 0; s < 8; ++s) {
    const int base = (s & 1) * 16384;   // A @ base, B @ base+8192
    #pragma unroll
    for (int i = 0; i < 4; ++i) {
      int flat = t * 4 + i * 1024;
      int row = flat >> 6, col = flat & 63;
      f16x4 ha, hb;
      ha[0] = (f16)ra[i].x; ha[1] = (f16)ra[i].y; ha[2] = (f16)ra[i].z; ha[3] = (f16)ra[i].w;
      hb[0] = (f16)rb[i].x; hb[1] = (f16)rb[i].y; hb[2] = (f16)rb[i].z; hb[3] = (f16)rb[i].w;
      int byte = row * 128 + ((col * 2) ^ ((row & 7) << 4));
      *reinterpret_cast<f16x4*>(lds + base + byte) = ha;
      *reinterpret_cast<f16x4*>(lds + base + 8192 + byte) = hb;
    }
    if (s < 7) LOADK((s + 1) * 64);   // in flight across compute
    __syncthreads();                  // single barrier per step (dbuf-safe)
    #pragma unroll
    for (int kh = 0; kh < 2; ++kh) {
      f16x8 af[2], bf[2];
      #pragma unroll
      for (int mi = 0; mi < 2; ++mi) {
        int row = wr * 32 + mi * 16 + fr;
        af[mi] = *reinterpret_cast<const f16x8*>(
            lds + base + row * 128 + ((kh * 64 + fq * 16) ^ ((row & 7) << 4)));
      }
      #pragma unroll
      for (int ni = 0; ni < 2; ++ni) {
        int row = wc * 32 + ni * 16 + fr;
        bf[ni] = *reinterpret_cast<const f16x8*>(
            lds + base + 8192 + row * 128 + ((kh * 64 + fq * 16) ^ ((row & 7) << 4)));
      }
      #pragma unroll
      for (int mi = 0; mi < 2; ++mi)
        #pragma unroll
        for (int ni = 0; ni < 2; ++ni)
          acc[mi][ni] = __builtin_amdgcn_mfma_f32_16x16x32_f16(
              af[mi], bf[ni], acc[mi][ni], 0, 0, 0);
    }
  }
#undef LOADK
  #pragma unroll
  for (int mi = 0; mi < 2; ++mi) {
    #pragma unroll
    for (int ni = 0; ni < 2; ++ni) {
      int row = rowA0 + wr * 32 + mi * 16 + fq * 4;
      int col = m0 + wc * 32 + ni * 16 + fr;
      #pragma unroll
      for (int r = 0; r < 4; ++r)
        kx[(size_t)(row + r) * DD + col] = (f16)acc[mi][ni][r];
    }
  }
}

// ---------------------------------------------------------------------------
// K2: score — 512 threads, 2l x 2q, T14 prefetch.  w held in REGISTERS per
// m-chunk (w16 L1-resident; deletes the wv LDS read -> 4 instead of 5 b128
// reads per inner iter, -20% LDS traffic).  mm loop fully unrolled so the
// rw[] index is static (no scratch).  sc output f16.
// ---------------------------------------------------------------------------
__global__ __launch_bounds__(512) void score6_kernel(
    const f16* __restrict__ kx,   // [8,1024,512] f16
    const f16* __restrict__ qh,   // [64,512] f16
    const f16* __restrict__ w16,  // [512] f16
    f16* __restrict__ sc,         // [8,64,1024] f16
    float* __restrict__ pmax) {   // [8,64,32] f32
  const int b = blockIdx.x & 7;
  const int l0 = (blockIdx.x >> 3) * 32;
  const int t = threadIdx.x;
  __shared__ __align__(16) char kxs[32 * 256];   // row*256 + (col2 ^ ((row&7)<<4))
  __shared__ __align__(16) char qhs[64 * 256];   // row*256 + (col2 ^ ((row&15)<<4))
  __shared__ float smax[64][17];
  const int qb = t & 31;
  const int lp = t >> 5;
  float acc[2][2] = {};
  uint4 rkx, rqh[2];

#define LOADM(M0)                                                              \
  do {                                                                         \
    {                                                                          \
      int row = t >> 4, col = (t & 15) * 8;                                    \
      rkx = *reinterpret_cast<const uint4*>(kx + (size_t)(b * LL + l0 + row) * DD + (M0) + col); \
    }                                                                          \
    _Pragma("unroll") for (int p = 0; p < 2; ++p) {                            \
      int slot = t + p * 512;                                                  \
      int row = slot >> 4, col = (slot & 15) * 8;                              \
      rqh[p] = *reinterpret_cast<const uint4*>(qh + (size_t)row * DD + (M0) + col); \
    }                                                                          \
  } while (0)

  LOADM(0);
  for (int m0 = 0; m0 < DD; m0 += 128) {
    // w chunk -> registers (L1-resident 1KB; issued before staging/barrier)
    F16x8u rw[16];
    #pragma unroll
    for (int i = 0; i < 16; ++i)
      rw[i].v = *reinterpret_cast<const f16x8*>(w16 + m0 + i * 8);
    {
      int row = t >> 4, cb = (t & 15) * 16;
      *reinterpret_cast<uint4*>(kxs + row * 256 + (cb ^ ((row & 7) << 4))) = rkx;
    }
    #pragma unroll
    for (int p = 0; p < 2; ++p) {
      int slot = t + p * 512;
      int row = slot >> 4, cb = (slot & 15) * 16;
      *reinterpret_cast<uint4*>(qhs + row * 256 + (cb ^ ((row & 15) << 4))) = rqh[p];
    }
    if (m0 < DD - 128) LOADM(m0 + 128);
    __syncthreads();
    #pragma unroll
    for (int mm = 0; mm < 128; mm += 8) {
      const int mb = mm * 2;
      F16x8u kv0, kv1;
      {
        int r0 = lp * 2, r1 = lp * 2 + 1;
        kv0.v = *reinterpret_cast<const f16x8*>(kxs + r0 * 256 + (mb ^ ((r0 & 7) << 4)));
        kv1.v = *reinterpret_cast<const f16x8*>(kxs + r1 * 256 + (mb ^ ((r1 & 7) << 4)));
      }
      const F16x8u wv = rw[mm >> 3];   // static index (full unroll)
      #pragma unroll
      for (int j = 0; j < 2; ++j) {
        int qr = qb + 32 * j;
        F16x8u qv, g0, g1;
        qv.v = *reinterpret_cast<const f16x8*>(qhs + qr * 256 + (mb ^ ((qr & 15) << 4)));
        f16x8 zz = {};
        g0.v = __builtin_elementwise_max(kv0.v + qv.v, zz);
        g1.v = __builtin_elementwise_max(kv1.v + qv.v, zz);
        #pragma unroll
        for (int c = 0; c < 4; ++c) {
          acc[0][j] = __builtin_amdgcn_fdot2(g0.h[c], wv.h[c], acc[0][j], false);
          acc[1][j] = __builtin_amdgcn_fdot2(g1.h[c], wv.h[c], acc[1][j], false);
        }
      }
    }
    __syncthreads();
  }
#undef LOADM
  #pragma unroll
  for (int i = 0; i < 2; ++i)
    #pragma unroll
    for (int j = 0; j < 2; ++j)
      sc[((size_t)b * L1 + qb + 32 * j) * LL + l0 + lp * 2 + i] = (f16)acc[i][j];
  #pragma unroll
  for (int j = 0; j < 2; ++j)
    smax[qb + 32 * j][lp] = fmaxf(acc[0][j], acc[1][j]);
  __syncthreads();
  if (t < 64) {
    float m = smax[t][0];
    #pragma unroll
    for (int i = 1; i < 16; ++i) m = fmaxf(m, smax[t][i]);
    pmax[((size_t)b * L1 + t) * 32 + (l0 >> 5)] = m;
  }
}

// ---------------------------------------------------------------------------
// K3: fused softmax + PV GEMM — 512 thr, ks-split; sc in f16.  (r13's fso3)
// ---------------------------------------------------------------------------
__global__ __launch_bounds__(512) void fso3_kernel(
    const f16* __restrict__ sc,     // [8,64,1024] f16
    const float* __restrict__ pmax, // [8,64,32] f32
    const float* __restrict__ v,    // [8,1024,512] f32
    float* __restrict__ out) {      // [8,64,512] f32
  __shared__ __align__(16) char es[64 * 256];
  __shared__ __align__(16) char vt[16 * 256];
  __shared__ float rowm[64];
  __shared__ float rowinv[64];
  __shared__ float spart[64][17];
  __shared__ f32x4 accbuf[4][64];
  const int t = threadIdx.x;
  const int lane = t & 63;
  const int w = t >> 6;
  const int fq = lane >> 4, fr = lane & 15;
  const int bid = blockIdx.x;
  const int b = bid & 7;
  const int d0 = (bid >> 3) * 16;
  const f16* scb = sc + (size_t)b * L1 * LL;
  const float* vb = v + (size_t)b * LL * DD;

  const int r0 = t >> 4;
  const int r1 = (t + 512) >> 4;
  const int ec8 = t & 15;
  const int vl = t >> 2;
  const int dq = (t & 3) * 4;
  uint4 rsc[2];
  float4 rv;

#define LOADC(LC)                                                              \
  do {                                                                         \
    rsc[0] = *reinterpret_cast<const uint4*>(scb + (size_t)r0 * LL + (LC) * 128 + ec8 * 8); \
    rsc[1] = *reinterpret_cast<const uint4*>(scb + (size_t)r1 * LL + (LC) * 128 + ec8 * 8); \
    rv = *reinterpret_cast<const float4*>(                                     \
        vb + (size_t)((LC) * 128 + vl) * DD + d0 + dq);                        \
  } while (0)

  LOADC(0);
  if (t < 64) {
    const float* pm = pmax + ((size_t)b * L1 + t) * 32;
    float4 m4 = *reinterpret_cast<const float4*>(pm);
    #pragma unroll
    for (int i = 1; i < 8; ++i) {
      float4 x = *reinterpret_cast<const float4*>(pm + i * 4);
      m4.x = fmaxf(m4.x, x.x); m4.y = fmaxf(m4.y, x.y);
      m4.z = fmaxf(m4.z, x.z); m4.w = fmaxf(m4.w, x.w);
    }
    rowm[t] = fmaxf(fmaxf(m4.x, m4.y), fmaxf(m4.z, m4.w));
  }
  __syncthreads();
  float rmv[2] = {rowm[r0], rowm[r1]};
  float spp[2] = {0.f, 0.f};
  f32x4 acc = {};
  const int qs = (w & 3) * 16;
  const int ksh = (w >> 2) * 2;

  for (int c = 0; c < 8; ++c) {
    #pragma unroll
    for (int p = 0; p < 2; ++p) {
      int q = p ? r1 : r0;
      U4H8 x; x.u = rsc[p];
      f16x8 h;
      #pragma unroll
      for (int j = 0; j < 8; ++j) {
        float e = __expf((float)x.v[j] - rmv[p]);
        spp[p] += e;
        h[j] = (f16)e;
      }
      int byte = q * 256 + ((ec8 * 16) ^ ((q & 7) << 4));
      *reinterpret_cast<f16x8*>(es + byte) = h;
    }
    {
      float vs[4] = {rv.x, rv.y, rv.z, rv.w};
      #pragma unroll
      for (int j = 0; j < 4; ++j) {
        int d = dq + j;
        int byte = d * 256 + ((2 * vl) ^ ((d & 7) << 4));
        *reinterpret_cast<f16*>(vt + byte) = (f16)vs[j];
      }
    }
    if (c < 7) LOADC(c + 1);
    __syncthreads();
    #pragma unroll
    for (int ki = 0; ki < 2; ++ki) {
      int ks = ksh + ki;
      int qa = qs + fr;
      int colb = ks * 64 + fq * 16;
      f16x8 a = *reinterpret_cast<const f16x8*>(es + qa * 256 + (colb ^ ((qa & 7) << 4)));
      f16x8 bb = *reinterpret_cast<const f16x8*>(vt + fr * 256 + (colb ^ ((fr & 7) << 4)));
      acc = __builtin_amdgcn_mfma_f32_16x16x32_f16(a, bb, acc, 0, 0, 0);
    }
    __syncthreads();
  }
#undef LOADC
  spart[r0][ec8] = spp[0];
  spart[r1][ec8] = spp[1];
  if (w >= 4) accbuf[w & 3][lane] = acc;
  __syncthreads();
  if (t < 64) {
    float S = 0.f;
    #pragma unroll
    for (int i = 0; i < 16; ++i) S += spart[t][i];
    rowinv[t] = 1.f / S;
  }
  __syncthreads();
  if (w < 4) {
    f32x4 ah = accbuf[w][lane];
    acc += ah;
    #pragma unroll
    for (int r = 0; r < 4; ++r) {
      int q = qs + fq * 4 + r;
      out[((size_t)b * L1 + q) * DD + d0 + fr] = acc[r] * rowinv[q];
    }
  }
}

// ---------------------------------------------------------------------------
extern "C" void kernel_launch(void* const* d_in, const int* in_sizes, int n_in,
                              void* d_out, int out_size, void* d_ws, size_t ws_size,
                              hipStream_t stream) {
  const float* query  = (const float*)d_in[0];  // [64,512]
  const float* keys   = (const float*)d_in[1];  // [8,1024,512]
  const float* values = (const float*)d_in[2];  // [8,1024,512]
  const float* Wx     = (const float*)d_in[3];  // [512,512]
  const float* Wh     = (const float*)d_in[4];  // [512,512]
  const float* bh     = (const float*)d_in[5];  // [512]
  const float* w      = (const float*)d_in[6];  // [512]
  float* out = (float*)d_out;                   // [8,64,512]

  char* ws = (char*)d_ws;
  f16*   kx   = (f16*)ws;                        // 8 MB
  f16*   qh   = (f16*)(ws + 8388608);            // 64 KB
  f16*   sc   = (f16*)(ws + 8454144);            // 1 MB (f16 scores)
  float* pmax = (float*)(ws + 9502720);          // 64 KB
  f16*   w16  = (f16*)(ws + 9568256);            // 1 KB

  kxqh_kernel<<<1032, 256, 0, stream>>>(keys, query, Wx, Wh, bh, w, kx, qh, w16);
  score6_kernel<<<256, 512, 0, stream>>>(kx, qh, w16, sc, pmax);
  fso3_kernel<<<256, 512, 0, stream>>>(sc, pmax, values, out);
}